// Round 1
// baseline (76.596 us; speedup 1.0000x reference)
//
#include <hip/hip_runtime.h>

// Problem constants from the reference
#define NS 32768   // N_SAMPLES
#define NI 16      // N_ITERS
#define KL 256     // KERNEL (atom length)
#define NF 512     // N_FRAMES
#define NA 256     // atom_selection inner dim
#define STEP 64    // NS / NF

// Swizzled LDS index for atom rows: idx + idx/32 breaks the 32-float-stride
// bank aliasing caused by the 32-contiguous-samples-per-thread output layout.
__device__ __forceinline__ int swz(int k) { return k + (k >> 5); }

__global__ __launch_bounds__(1024) void fused_impulse_conv(
    const float* __restrict__ asel,   // [NI, NA]
    const float* __restrict__ amps,   // [NI, 1]
    const float* __restrict__ sched,  // [NI, NF]
    const float* __restrict__ d,      // [NA, KL]
    float* __restrict__ out)          // [NS]
{
    __shared__ int   s_p[NI];                    // sample position of delta i
    __shared__ float s_atom[NI][KL + (KL >> 5)]; // 264 floats/row, swizzled
    __shared__ float s_red[16];

    const int tid  = threadIdx.x;
    const int wave = tid >> 6;
    const int lane = tid & 63;

    // ---- Phase 0: wave i handles iter i (16 waves, 16 iters) ----
    {
        const int i = wave;

        // argmax over sched row (512 elems, 8/lane). Within-lane: keep first
        // (earliest k) on ties; cross-lane: tie-break toward smaller index,
        // matching jnp.argmax first-occurrence semantics.
        float bv = -INFINITY; int bi = 1 << 30;
        for (int k = lane; k < NF; k += 64) {
            float v = sched[i * NF + k];
            if (v > bv) { bv = v; bi = k; }
        }
        for (int off = 32; off > 0; off >>= 1) {
            float ov = __shfl_down(bv, off);
            int   oi = __shfl_down(bi, off);
            if (ov > bv || (ov == bv && oi < bi)) { bv = ov; bi = oi; }
        }
        int p = __shfl(bi, 0) * STEP;
        if (lane == 0) s_p[i] = p;

        // argmax over atom_selection row (256 elems, 4/lane)
        bv = -INFINITY; bi = 1 << 30;
        for (int k = lane; k < NA; k += 64) {
            float v = asel[i * NA + k];
            if (v > bv) { bv = v; bi = k; }
        }
        for (int off = 32; off > 0; off >>= 1) {
            float ov = __shfl_down(bv, off);
            int   oi = __shfl_down(bi, off);
            if (ov > bv || (ov == bv && oi < bi)) { bv = ov; bi = oi; }
        }
        const int a = __shfl(bi, 0);

        // stage amp-scaled atom row into swizzled LDS
        const float amp = amps[i];
        for (int k = lane; k < KL; k += 64)
            s_atom[i][swz(k)] = amp * d[a * KL + k];
    }
    __syncthreads();

    // ---- Phase 1: each thread owns 32 contiguous samples [t0, t0+32) ----
    const int t0 = tid << 5;
    float vals[32];
#pragma unroll
    for (int j = 0; j < 32; j++) vals[j] = 0.f;

    for (int i = 0; i < NI; i++) {
        const int p  = s_p[i];
        const int lo = p - t0;              // atom start relative to window
        if (lo >= 32 || lo <= -KL) continue; // no overlap with this window
#pragma unroll
        for (int j = 0; j < 32; j++) {
            const int off = j - lo;          // = (t0 + j) - p
            if ((unsigned)off < (unsigned)KL)
                vals[j] += s_atom[i][swz(off)];
        }
    }

    // ---- Phase 2: global abs-max (wave shuffle + LDS) ----
    float mx = 0.f;
#pragma unroll
    for (int j = 0; j < 32; j++) mx = fmaxf(mx, fabsf(vals[j]));
    for (int off = 32; off > 0; off >>= 1)
        mx = fmaxf(mx, __shfl_down(mx, off));
    if (lane == 0) s_red[wave] = mx;
    __syncthreads();
    if (wave == 0) {
        float m = (lane < 16) ? s_red[lane] : 0.f;
        for (int off = 8; off > 0; off >>= 1)
            m = fmaxf(m, __shfl_down(m, off));
        if (lane == 0) s_red[0] = m + 1e-8f;
    }
    __syncthreads();
    const float denom = s_red[0];

    // ---- Phase 3: normalize (IEEE divide, matching reference) + store ----
#pragma unroll
    for (int j = 0; j < 32; j += 4) {
        float4 v;
        v.x = vals[j + 0] / denom;
        v.y = vals[j + 1] / denom;
        v.z = vals[j + 2] / denom;
        v.w = vals[j + 3] / denom;
        *reinterpret_cast<float4*>(&out[t0 + j]) = v;  // 128B-aligned
    }
}

extern "C" void kernel_launch(void* const* d_in, const int* in_sizes, int n_in,
                              void* d_out, int out_size, void* d_ws, size_t ws_size,
                              hipStream_t stream) {
    // Input order per setup_inputs(): x (unused), atom_selection, amps,
    // sched_params, d
    const float* asel  = (const float*)d_in[1];
    const float* amps  = (const float*)d_in[2];
    const float* sched = (const float*)d_in[3];
    const float* d     = (const float*)d_in[4];
    float* out = (float*)d_out;

    fused_impulse_conv<<<1, 1024, 0, stream>>>(asel, amps, sched, d, out);
}

// Round 3
// 72.372 us; speedup vs baseline: 1.0584x; 1.0584x over previous
//
#include <hip/hip_runtime.h>

// Problem constants from the reference
#define NS 32768   // N_SAMPLES
#define NI 16      // N_ITERS
#define KL 256     // KERNEL (atom length)
#define NF 512     // N_FRAMES
#define NA 256     // atom_selection inner dim
#define STEP 64    // NS / NF

// Swizzled LDS index for atom rows: idx + idx/32 breaks the 32-float-stride
// bank aliasing caused by the 32-contiguous-samples-per-thread output layout.
__device__ __forceinline__ int swz(int k) { return k + (k >> 5); }

// argmax shuffle-reduce across 64 lanes, first-occurrence tie-break
// (cross-lane index order is consistent because loads use blocked layout).
__device__ __forceinline__ void wave_argmax(float& bv, int& bi) {
    for (int off = 32; off > 0; off >>= 1) {
        float ov = __shfl_down(bv, off);
        int   oi = __shfl_down(bi, off);
        if (ov > bv || (ov == bv && oi < bi)) { bv = ov; bi = oi; }
    }
}

__global__ __launch_bounds__(1024) void fused_impulse_conv(
    const float* __restrict__ asel,   // [NI, NA]
    const float* __restrict__ amps,   // [NI, 1]
    const float* __restrict__ sched,  // [NI, NF]
    const float* __restrict__ d,      // [NA, KL]
    float* __restrict__ out)          // [NS]
{
    __shared__ int   s_p[NI];                    // sample position of delta i
    __shared__ float s_atom[NI][KL + (KL >> 5)]; // 264 floats/row, swizzled
    __shared__ float s_red[16];

    const int tid  = threadIdx.x;
    const int wave = tid >> 6;
    const int lane = tid & 63;
    const int i    = wave;                       // wave i handles iter i

    // ---- Phase 0: issue ALL independent loads up front (1st memory round).
    // Blocked float4 layout: lane L owns indices [4L, 4L+4) (and +256 for sched).
    const float4* sched4 = reinterpret_cast<const float4*>(sched + i * NF);
    const float4* asel4  = reinterpret_cast<const float4*>(asel + i * NA);
    float4 sA = sched4[lane];        // sched idx 4*lane + j
    float4 sB = sched4[lane + 64];   // sched idx 256 + 4*lane + j
    float4 aV = asel4[lane];         // asel  idx 4*lane + j
    const float amp = amps[i];

    // asel argmax FIRST so the dependent d-row load issues earliest.
    float bv = aV.x; int bi = 4 * lane;
    if (aV.y > bv) { bv = aV.y; bi = 4 * lane + 1; }
    if (aV.z > bv) { bv = aV.z; bi = 4 * lane + 2; }
    if (aV.w > bv) { bv = aV.w; bi = 4 * lane + 3; }
    wave_argmax(bv, bi);
    const int a = __shfl(bi, 0);

    // 2nd (final) memory round: the selected atom row.
    const float4 dv = reinterpret_cast<const float4*>(d + a * KL)[lane];

    // sched argmax while the d-row load is in flight.
    bv = sA.x; bi = 4 * lane;
    if (sA.y > bv) { bv = sA.y; bi = 4 * lane + 1; }
    if (sA.z > bv) { bv = sA.z; bi = 4 * lane + 2; }
    if (sA.w > bv) { bv = sA.w; bi = 4 * lane + 3; }
    if (sB.x > bv) { bv = sB.x; bi = 256 + 4 * lane; }
    if (sB.y > bv) { bv = sB.y; bi = 256 + 4 * lane + 1; }
    if (sB.z > bv) { bv = sB.z; bi = 256 + 4 * lane + 2; }
    if (sB.w > bv) { bv = sB.w; bi = 256 + 4 * lane + 3; }
    wave_argmax(bv, bi);
    if (lane == 0) s_p[i] = __shfl(bi, 0) * STEP;

    // Stage amp-scaled atom row (4 consecutive elems/lane; swz keeps them
    // contiguous since the 4-group never straddles a 32-boundary).
    const int k0 = 4 * lane;
    s_atom[i][swz(k0) + 0] = amp * dv.x;
    s_atom[i][swz(k0) + 1] = amp * dv.y;
    s_atom[i][swz(k0) + 2] = amp * dv.z;
    s_atom[i][swz(k0) + 3] = amp * dv.w;
    __syncthreads();

    // ---- Phase 1: each thread owns 32 contiguous samples [t0, t0+32) ----
    const int t0 = tid << 5;
    float vals[32];
#pragma unroll
    for (int j = 0; j < 32; j++) vals[j] = 0.f;

    for (int ii = 0; ii < NI; ii++) {
        const int p  = s_p[ii];
        const int lo = p - t0;               // atom start relative to window
        if (lo >= 32 || lo <= -KL) continue; // no overlap with this window
#pragma unroll
        for (int j = 0; j < 32; j++) {
            const int off = j - lo;          // = (t0 + j) - p
            if ((unsigned)off < (unsigned)KL)
                vals[j] += s_atom[ii][swz(off)];
        }
    }

    // ---- Phase 2: global abs-max (wave shuffle + LDS) ----
    float mx = 0.f;
#pragma unroll
    for (int j = 0; j < 32; j++) mx = fmaxf(mx, fabsf(vals[j]));
    for (int off = 32; off > 0; off >>= 1)
        mx = fmaxf(mx, __shfl_down(mx, off));
    if (lane == 0) s_red[wave] = mx;
    __syncthreads();
    if (wave == 0) {
        float m = (lane < 16) ? s_red[lane] : 0.f;
        for (int off = 8; off > 0; off >>= 1)
            m = fmaxf(m, __shfl_down(m, off));
        if (lane == 0) s_red[0] = m + 1e-8f;
    }
    __syncthreads();
    const float denom = s_red[0];

    // ---- Phase 3: normalize (IEEE divide, matching reference) + store ----
#pragma unroll
    for (int j = 0; j < 32; j += 4) {
        float4 v;
        v.x = vals[j + 0] / denom;
        v.y = vals[j + 1] / denom;
        v.z = vals[j + 2] / denom;
        v.w = vals[j + 3] / denom;
        *reinterpret_cast<float4*>(&out[t0 + j]) = v;  // 128B-aligned
    }
}

extern "C" void kernel_launch(void* const* d_in, const int* in_sizes, int n_in,
                              void* d_out, int out_size, void* d_ws, size_t ws_size,
                              hipStream_t stream) {
    // Input order per setup_inputs(): x (unused), atom_selection, amps,
    // sched_params, d
    const float* asel  = (const float*)d_in[1];
    const float* amps  = (const float*)d_in[2];
    const float* sched = (const float*)d_in[3];
    const float* d     = (const float*)d_in[4];
    float* out = (float*)d_out;

    fused_impulse_conv<<<1, 1024, 0, stream>>>(asel, amps, sched, d, out);
}